// Round 23
// baseline (132.809 us; speedup 1.0000x reference)
//
#include <hip/hip_runtime.h>
#include <hip/hip_fp16.h>

#define N_NODES 100000
#define N_EDGES 1600000
#define NFEAT 128
#define NHID 64
#define NOUT 32

#define NPB 256                                   // nodes per bucket (node >> 8)
#define NB ((N_NODES + NPB - 1) / NPB)            // 391 buckets
#define CAP 4608                                  // bucket window capacity
#define NSB 25                                    // super-buckets (node >> 12)
#define SCAPA 69632                               // super window capacity (17*4096; mean 64000, +18 sigma)
#define CCH 4096                                  // edges per scatter chunk
#define NCH ((N_EDGES + CCH - 1) / CCH)           // 391
#define SBCH 17                                   // pass-B chunks per super window
#define G1B ((N_NODES / 16 + 7) / 8)              // 782 gemm1 blocks (8 tiles each)

typedef _Float16 half8 __attribute__((ext_vector_type(8)));
typedef float floatx4 __attribute__((ext_vector_type(4)));

// wave-level inclusive scan (64 lanes)
__device__ __forceinline__ int wave_incl_scan(int v, int lane) {
#pragma unroll
    for (int d = 1; d < 64; d <<= 1) {
        int t = __shfl_up(v, d, 64);
        if (lane >= d) v += t;
    }
    return v;
}
// exclusive prefix over a 512-thread block (per-thread value tsum).
__device__ __forceinline__ int block_excl_scan_512(int tsum, int tid, int* w8) {
    const int lane = tid & 63, wid = tid >> 6;
    int incl = wave_incl_scan(tsum, lane);
    if (lane == 63) w8[wid] = incl;
    __syncthreads();
    int wbase = 0;
#pragma unroll
    for (int i = 0; i < 7; ++i)
        if (wid > i) wbase += w8[i];
    return wbase + incl - tsum;
}

// ---------------------------------------------------------------
// prep: blocks 0-15 W1->A-frags; 16-19 W2->A-frags; rest init
// gcurB[NB] and gcurA[NSB].
// ---------------------------------------------------------------
__global__ __launch_bounds__(64) void prep_kernel(const float* __restrict__ W1,
                                                  const float* __restrict__ W2,
                                                  __half* __restrict__ wfrag,
                                                  __half* __restrict__ w2frag,
                                                  int* __restrict__ gcurA,
                                                  int* __restrict__ gcurB) {
    const int l = threadIdx.x;
    const int b = blockIdx.x;
    if (b < 16) {
        const int ks = b >> 2, ct = b & 3;
        const int kb = ks * 32 + (l >> 4) * 8;
        const int c  = ct * 16 + (l & 15);
        union { __half2 h2[4]; uint4 u; } pk;
#pragma unroll
        for (int j = 0; j < 4; ++j)
            pk.h2[j] = __floats2half2_rn(W1[(kb + 2 * j) * NHID + c],
                                         W1[(kb + 2 * j + 1) * NHID + c]);
        *(uint4*)&wfrag[((size_t)b * 64 + l) * 8] = pk.u;
    } else if (b < 20) {
        const int bb = b - 16;
        const int ks = bb >> 1, ct = bb & 1;
        const int kb = ks * 32 + (l >> 4) * 8;
        const int c  = ct * 16 + (l & 15);
        union { __half2 h2[4]; uint4 u; } pk;
#pragma unroll
        for (int j = 0; j < 4; ++j)
            pk.h2[j] = __floats2half2_rn(W2[(kb + 2 * j) * NOUT + c],
                                         W2[(kb + 2 * j + 1) * NOUT + c]);
        *(uint4*)&w2frag[((size_t)bb * 64 + l) * 8] = pk.u;
    } else {
        int i = (b - 20) * 64 + l;
        if (i < NB) gcurB[i] = i * CAP;
        else if (i < NB + NSB) gcurA[i - NB] = (i - NB) * SCAPA;
    }
}

// ---------------------------------------------------------------
// fused (512 threads): blocks [0,NCH) = radix pass A (scatter edges
// into 25 super-bucket windows; runs ~164 recs = line-efficient);
// blocks [NCH,..) = MFMA gemm1 (8 tiles/block).
// pass-A record: x = src(17b) | (node & 4095) << 17 ; y = val f32
// ---------------------------------------------------------------
__global__ __launch_bounds__(512) void g1cs_kernel(const float* __restrict__ x,
                                                   const __half* __restrict__ wfrag,
                                                   __half* __restrict__ support,
                                                   const float* __restrict__ vals,
                                                   const int* __restrict__ src,
                                                   const int* __restrict__ dst,
                                                   int* __restrict__ gcurA,
                                                   uint2* __restrict__ recsA) {
    __shared__ int cnt[32];
    __shared__ int pos[32];
    const int tid = threadIdx.x;

    if (blockIdx.x < NCH) {
        const int cbase0 = blockIdx.x * CCH;
        if (tid < 32) cnt[tid] = 0;
        int dstv[CCH / 512];
        __syncthreads();
#pragma unroll
        for (int k = 0; k < CCH / 512; ++k) {
            int e = cbase0 + k * 512 + tid;
            int d = (e < N_EDGES) ? dst[e] : -1;
            dstv[k] = d;
            if (d >= 0) atomicAdd(&cnt[d >> 12], 1);
        }
        __syncthreads();
        if (tid < NSB) {
            int c = cnt[tid];
            pos[tid] = c ? atomicAdd(&gcurA[tid], c) : 0;
        }
        __syncthreads();
#pragma unroll
        for (int k = 0; k < CCH / 512; ++k) {
            int e = cbase0 + k * 512 + tid;
            int d = dstv[k];
            if (d >= 0) {
                int sb = d >> 12;
                int slot = atomicAdd(&pos[sb], 1);
                if (slot < (sb + 1) * SCAPA)
                    recsA[slot] = make_uint2((unsigned)src[e] |
                                             ((unsigned)(d & 4095) << 17),
                                             __float_as_uint(vals[e]));
            }
        }
    } else {
        // ------- MFMA gemm1: support = x @ W1 (8 tiles per block) -------
        const int lane = tid & 63;
        const int tile = (blockIdx.x - NCH) * 8 + (tid >> 6);
        const int n0 = tile * 16;
        if (n0 >= N_NODES) return;

        half8 a[4][4];
#pragma unroll
        for (int ks = 0; ks < 4; ++ks)
#pragma unroll
            for (int ct = 0; ct < 4; ++ct)
                a[ks][ct] = *(const half8*)&wfrag[((size_t)(ks * 4 + ct) * 64 + lane) * 8];

        floatx4 acc[4];
#pragma unroll
        for (int ct = 0; ct < 4; ++ct) acc[ct] = (floatx4){0.f, 0.f, 0.f, 0.f};

        const int node = n0 + (lane & 15);
        const float* xrow = x + (size_t)node * NFEAT + (lane >> 4) * 8;

#pragma unroll
        for (int ks = 0; ks < 4; ++ks) {
            float4 f0 = *(const float4*)(xrow + ks * 32);
            float4 f1 = *(const float4*)(xrow + ks * 32 + 4);
            union { __half2 h2[4]; half8 v; } bv;
            bv.h2[0] = __floats2half2_rn(f0.x, f0.y);
            bv.h2[1] = __floats2half2_rn(f0.z, f0.w);
            bv.h2[2] = __floats2half2_rn(f1.x, f1.y);
            bv.h2[3] = __floats2half2_rn(f1.z, f1.w);
#pragma unroll
            for (int ct = 0; ct < 4; ++ct)
                acc[ct] = __builtin_amdgcn_mfma_f32_16x16x32_f16(a[ks][ct], bv.v, acc[ct], 0, 0, 0);
        }

        __half* srow = support + (size_t)node * NHID + (lane >> 4) * 4;
#pragma unroll
        for (int ct = 0; ct < 4; ++ct) {
            union { __half2 h2[2]; uint2 u; } pk;
            pk.h2[0] = __floats2half2_rn(acc[ct][0], acc[ct][1]);
            pk.h2[1] = __floats2half2_rn(acc[ct][2], acc[ct][3]);
            *(uint2*)&srow[ct * 16] = pk.u;
        }
    }
}

// ---------------------------------------------------------------
// radix pass B (512 threads): scatter each super window into its
// 16 buckets (runs ~256 recs = 2KB, line-efficient).
// out record: x = src(17b) | dl(8b)<<17 ; y = val f32
// ---------------------------------------------------------------
__global__ __launch_bounds__(512) void passB_kernel(const int* __restrict__ gcurA,
                                                    const uint2* __restrict__ recsA,
                                                    int* __restrict__ gcurB,
                                                    uint2* __restrict__ recsB) {
    __shared__ int cnt[16];
    __shared__ int pos[16];
    const int tid = threadIdx.x;
    const int sb = blockIdx.x / SBCH;
    const int ch = blockIdx.x - sb * SBCH;
    const int base = sb * SCAPA + ch * 4096;
    const int fill = gcurA[sb];
    const int end = min(base + 4096, fill);

    if (tid < 16) cnt[tid] = 0;
    uint2 rr[4096 / 512];
    __syncthreads();
#pragma unroll
    for (int k = 0; k < 4096 / 512; ++k) {
        int i = base + k * 512 + tid;
        if (i < end) {
            uint2 r = recsA[i];
            rr[k] = r;
            atomicAdd(&cnt[(r.x >> 25) & 15], 1);
        }
    }
    __syncthreads();
    if (tid < 16) {
        int c = cnt[tid];
        pos[tid] = c ? atomicAdd(&gcurB[sb * 16 + tid], c) : 0;
    }
    __syncthreads();
#pragma unroll
    for (int k = 0; k < 4096 / 512; ++k) {
        int i = base + k * 512 + tid;
        if (i < end) {
            uint2 r = rr[k];
            int b16 = (r.x >> 25) & 15;
            int gb = sb * 16 + b16;
            int slot = atomicAdd(&pos[b16], 1);
            if (slot < (gb + 1) * CAP)
                recsB[slot] = make_uint2((r.x & 0x1FFFFu) |
                                         (((r.x >> 17) & 255u) << 17), r.y);
        }
    }
}

// ---------------------------------------------------------------
// fine sort (512 threads): counting-sort each bucket window into
// exact node order; PACK record to 4B: src(17) | fp16val sans sign(15).
// (adj_vals >= 0 so the fp16 sign bit is always 0 -> exact.)
// ---------------------------------------------------------------
__global__ __launch_bounds__(512) void fine_sort_kernel(const int* __restrict__ gcur,
                                                        const uint2* __restrict__ recsC,
                                                        unsigned* __restrict__ recs2,
                                                        int* __restrict__ offs,
                                                        int* __restrict__ ends) {
    __shared__ int cnt[NPB];
    __shared__ int cur[NPB];
    __shared__ int w8[8];
    const int tid = threadIdx.x;
    const int b = blockIdx.x;
    const int s = b * CAP;
    const int e = min(gcur[b], s + CAP);
    if (tid < NPB) cnt[tid] = 0;
    __syncthreads();
    for (int i = s + tid; i < e; i += 512)
        atomicAdd(&cnt[(recsC[i].x >> 17) & (NPB - 1)], 1);
    __syncthreads();
    int v = (tid < NPB) ? cnt[tid] : 0;
    int excl = block_excl_scan_512(v, tid, w8);
    if (tid < NPB) {
        cur[tid] = excl;
        const int node = b * NPB + tid;
        if (node < N_NODES) {
            offs[node] = s + excl;
            ends[node] = s + excl + v;
        }
    }
    __syncthreads();
    for (int i = s + tid; i < e; i += 512) {
        uint2 r = recsC[i];
        int dl = (r.x >> 17) & (NPB - 1);
        unsigned hb = (unsigned)__half_as_ushort(__float2half(__uint_as_float(r.y))) & 0x7FFFu;
        int p = atomicAdd(&cur[dl], 1);
        recs2[s + p] = (r.x & 0x1FFFFu) | (hb << 17);
    }
}

// ---------------------------------------------------------------
// SpMM1: h[d,:64] (fp16) = relu( sum val*support[src,:] + b1 )
// wave per node; 8 lanes/edge x 16B; packed 4B records; __hfma2.
// ---------------------------------------------------------------
__global__ __launch_bounds__(256) void spmm1_kernel(const int* __restrict__ offs,
                                                    const int* __restrict__ ends,
                                                    const unsigned* __restrict__ recs,
                                                    const __half* __restrict__ dense,
                                                    const float* __restrict__ b1,
                                                    __half* __restrict__ h) {
    __shared__ float red[4][8][65];
    const int tid = threadIdx.x;
    const int lane = tid & 63;
    const int wid = tid >> 6;
    const int d = blockIdx.x * 4 + wid;
    if (d >= N_NODES) return;
    const int g = lane >> 3, q = lane & 7;
    __half2 hacc[4];
#pragma unroll
    for (int j = 0; j < 4; ++j) hacc[j] = __half2half2(__float2half(0.f));

    const int start = offs[d], end = ends[d];
    for (int e = start + g; e < end; e += 8) {
        unsigned r = recs[e];
        __half2 hv2 = __half2half2(__ushort_as_half((unsigned short)(r >> 17)));
        union { uint4 u; __half2 h2[4]; } rw;
        rw.u = *(const uint4*)((const char*)dense + ((size_t)(r & 0x1FFFFu) << 7) + (q << 4));
#pragma unroll
        for (int j = 0; j < 4; ++j)
            hacc[j] = __hfma2(rw.h2[j], hv2, hacc[j]);
    }
#pragma unroll
    for (int j = 0; j < 4; ++j) {
        float2 f = __half22float2(hacc[j]);
        red[wid][g][q * 8 + 2 * j]     = f.x;
        red[wid][g][q * 8 + 2 * j + 1] = f.y;
    }
    __builtin_amdgcn_wave_barrier();
    float s = 0.f;
#pragma unroll
    for (int gg = 0; gg < 8; ++gg) s += red[wid][gg][lane];
    float hv = fmaxf(s + b1[lane], 0.f);
    h[(size_t)d * NHID + lane] = __float2half(hv);
}

// ---------------------------------------------------------------
// GEMM2 (MFMA): s2[N,32] (fp16) = h[N,64] (fp16) @ W2[64,32]
// ---------------------------------------------------------------
__global__ __launch_bounds__(256) void gemm2_kernel(const __half* __restrict__ h,
                                                    const __half* __restrict__ w2frag,
                                                    __half* __restrict__ s2) {
    const int lane = threadIdx.x & 63;
    const int tile = blockIdx.x * 4 + (threadIdx.x >> 6);
    const int n0 = tile * 16;
    if (n0 >= N_NODES) return;

    half8 a[2][2];
#pragma unroll
    for (int ks = 0; ks < 2; ++ks)
#pragma unroll
        for (int ct = 0; ct < 2; ++ct)
            a[ks][ct] = *(const half8*)&w2frag[((size_t)(ks * 2 + ct) * 64 + lane) * 8];

    floatx4 acc[2];
#pragma unroll
    for (int ct = 0; ct < 2; ++ct) acc[ct] = (floatx4){0.f, 0.f, 0.f, 0.f};

    const int node = n0 + (lane & 15);
    const __half* hrow = h + (size_t)node * NHID + (lane >> 4) * 8;

#pragma unroll
    for (int ks = 0; ks < 2; ++ks) {
        half8 bv = *(const half8*)(hrow + ks * 32);
#pragma unroll
        for (int ct = 0; ct < 2; ++ct)
            acc[ct] = __builtin_amdgcn_mfma_f32_16x16x32_f16(a[ks][ct], bv, acc[ct], 0, 0, 0);
    }

    __half* srow = s2 + (size_t)node * NOUT + (lane >> 4) * 4;
#pragma unroll
    for (int ct = 0; ct < 2; ++ct) {
        union { __half2 h2[2]; uint2 u; } pk;
        pk.h2[0] = __floats2half2_rn(acc[ct][0], acc[ct][1]);
        pk.h2[1] = __floats2half2_rn(acc[ct][2], acc[ct][3]);
        *(uint2*)&srow[ct * 16] = pk.u;
    }
}

// ---------------------------------------------------------------
// SpMM2: out[d,:32] (fp32) = sum val*s2[src,:] + b2
// wave per node; 4 lanes/edge x 16B; packed 4B records; __hfma2.
// ---------------------------------------------------------------
__global__ __launch_bounds__(256) void spmm2_kernel(const int* __restrict__ offs,
                                                    const int* __restrict__ ends,
                                                    const unsigned* __restrict__ recs,
                                                    const __half* __restrict__ dense,
                                                    const float* __restrict__ b2,
                                                    float* __restrict__ out) {
    __shared__ float red[4][16][33];
    const int tid = threadIdx.x;
    const int lane = tid & 63;
    const int wid = tid >> 6;
    const int d = blockIdx.x * 4 + wid;
    if (d >= N_NODES) return;
    const int g = lane >> 2, q4 = lane & 3;
    __half2 hacc[4];
#pragma unroll
    for (int j = 0; j < 4; ++j) hacc[j] = __half2half2(__float2half(0.f));

    const int start = offs[d], end = ends[d];
    const char* dbase = (const char*)dense + (q4 << 4);
    for (int e = start + g; e < end; e += 16) {
        unsigned r = recs[e];
        __half2 hv2 = __half2half2(__ushort_as_half((unsigned short)(r >> 17)));
        union { uint4 u; __half2 h2[4]; } rw;
        rw.u = *(const uint4*)(dbase + ((size_t)(r & 0x1FFFFu) << 6));
#pragma unroll
        for (int j = 0; j < 4; ++j)
            hacc[j] = __hfma2(rw.h2[j], hv2, hacc[j]);
    }
#pragma unroll
    for (int j = 0; j < 4; ++j) {
        float2 f = __half22float2(hacc[j]);
        red[wid][g][q4 * 8 + 2 * j]     = f.x;
        red[wid][g][q4 * 8 + 2 * j + 1] = f.y;
    }
    __builtin_amdgcn_wave_barrier();
    const int c = lane & 31, chunk = lane >> 5;
    float s = 0.f;
#pragma unroll
    for (int t = 0; t < 8; ++t) s += red[wid][chunk * 8 + t][c];
    s += __shfl_xor(s, 32, 64);
    if (chunk == 0) out[(size_t)d * NOUT + c] = s + b2[c];
}

extern "C" void kernel_launch(void* const* d_in, const int* in_sizes, int n_in,
                              void* d_out, int out_size, void* d_ws, size_t ws_size,
                              hipStream_t stream) {
    const float* x        = (const float*)d_in[0];
    const float* adj_vals = (const float*)d_in[1];
    const float* W1       = (const float*)d_in[2];
    const float* b1       = (const float*)d_in[3];
    const float* W2       = (const float*)d_in[4];
    const float* b2       = (const float*)d_in[5];
    const int*   esrc     = (const int*)d_in[6];
    const int*   edst     = (const int*)d_in[7];
    float*       out      = (float*)d_out;

    // ws layout (~62 MB, all regions rewritten every call):
    //   support[12.8MB] (s2 aliases; dead after spmm1) | h[12.8MB]
    //   recsA[NSB*SCAPA*8 = 13.93MB] | recsB[NB*CAP*8 = 14.41MB]
    //   recs2[NB*CAP*4 = 7.2MB] | offs | ends | gcurA | gcurB | frags
    char* W = (char*)d_ws;
    __half*   support = (__half*)W;
    __half*   h       = (__half*)(W + 12800000);
    uint2*    recsA   = (uint2*)(W + 25600000);
    uint2*    recsB   = (uint2*)(W + 25600000 + (size_t)NSB * SCAPA * 8);
    unsigned* recs2   = (unsigned*)(W + 25600000 + (size_t)NSB * SCAPA * 8
                                    + (size_t)NB * CAP * 8);
    int*      IW      = (int*)(W + 25600000 + (size_t)NSB * SCAPA * 8
                               + (size_t)NB * CAP * 12);
    int*      offs    = IW;                      // N
    int*      ends    = IW + 100032;             // N
    int*      gcurA   = IW + 200064;             // NSB
    int*      gcurB   = gcurA + 64;              // NB
    __half*   wfrag   = (__half*)(gcurB + 512);  // 8192 halves
    __half*   w2frag  = wfrag + 8192;            // 2048 halves
    __half*   s2      = support;

    // 1. prep: W1/W2 fragment swizzle + gcurA/gcurB init
    prep_kernel<<<20 + (NB + NSB + 63) / 64, 64, 0, stream>>>(W1, W2, wfrag, w2frag,
                                                              gcurA, gcurB);

    // 2. fused: radix pass A | MFMA gemm1
    g1cs_kernel<<<NCH + G1B, 512, 0, stream>>>(x, wfrag, support,
                                               adj_vals, esrc, edst, gcurA, recsA);

    // 3. radix pass B: super windows -> bucket windows
    passB_kernel<<<NSB * SBCH, 512, 0, stream>>>(gcurA, recsA, gcurB, recsB);

    // 4. fine sort -> packed recs2, offs/ends
    fine_sort_kernel<<<NB, 512, 0, stream>>>(gcurB, recsB, recs2, offs, ends);

    // 5. h = relu(A @ support + b1)
    spmm1_kernel<<<(N_NODES + 3) / 4, 256, 0, stream>>>(offs, ends, recs2,
                                                        support, b1, h);

    // 6. s2 = h @ W2  (MFMA, into support region)
    gemm2_kernel<<<(N_NODES / 16 + 3) / 4, 256, 0, stream>>>(h, w2frag, s2);

    // 7. out = A @ s2 + b2
    spmm2_kernel<<<(N_NODES + 3) / 4, 256, 0, stream>>>(offs, ends, recs2,
                                                        s2, b2, out);
}

// Round 24
// 131.133 us; speedup vs baseline: 1.0128x; 1.0128x over previous
//
#include <hip/hip_runtime.h>
#include <hip/hip_fp16.h>

#define N_NODES 100000
#define N_EDGES 1600000
#define NFEAT 128
#define NHID 64
#define NOUT 32

#define NPB 256                                   // nodes per bucket (dst >> 8)
#define NB ((N_NODES + NPB - 1) / NPB)            // 391 buckets
#define CAP 4608                                  // bucket window capacity
#define CCH 4096                                  // edges per scatter chunk
#define NCH ((N_EDGES + CCH - 1) / CCH)           // 391
#define G1B ((N_NODES / 16 + 7) / 8)              // 782 gemm1 blocks (8 tiles each)

typedef _Float16 half8 __attribute__((ext_vector_type(8)));
typedef float floatx4 __attribute__((ext_vector_type(4)));
typedef float floatx2 __attribute__((ext_vector_type(2)));

// wave-level inclusive scan (64 lanes)
__device__ __forceinline__ int wave_incl_scan(int v, int lane) {
#pragma unroll
    for (int d = 1; d < 64; d <<= 1) {
        int t = __shfl_up(v, d, 64);
        if (lane >= d) v += t;
    }
    return v;
}
// exclusive prefix over a 512-thread block (per-thread value tsum).
__device__ __forceinline__ int block_excl_scan_512(int tsum, int tid, int* w8) {
    const int lane = tid & 63, wid = tid >> 6;
    int incl = wave_incl_scan(tsum, lane);
    if (lane == 63) w8[wid] = incl;
    __syncthreads();
    int wbase = 0;
#pragma unroll
    for (int i = 0; i < 7; ++i)
        if (wid > i) wbase += w8[i];
    return wbase + incl - tsum;
}

// ---------------------------------------------------------------
// prep: blocks 0-15 W1->A-frags; 16-19 W2->A-frags; rest init gcur.
// ---------------------------------------------------------------
__global__ __launch_bounds__(64) void prep_kernel(const float* __restrict__ W1,
                                                  const float* __restrict__ W2,
                                                  __half* __restrict__ wfrag,
                                                  __half* __restrict__ w2frag,
                                                  int* __restrict__ gcur) {
    const int l = threadIdx.x;
    const int b = blockIdx.x;
    if (b < 16) {
        const int ks = b >> 2, ct = b & 3;
        const int kb = ks * 32 + (l >> 4) * 8;
        const int c  = ct * 16 + (l & 15);
        union { __half2 h2[4]; uint4 u; } pk;
#pragma unroll
        for (int j = 0; j < 4; ++j)
            pk.h2[j] = __floats2half2_rn(W1[(kb + 2 * j) * NHID + c],
                                         W1[(kb + 2 * j + 1) * NHID + c]);
        *(uint4*)&wfrag[((size_t)b * 64 + l) * 8] = pk.u;
    } else if (b < 20) {
        const int bb = b - 16;
        const int ks = bb >> 1, ct = bb & 1;
        const int kb = ks * 32 + (l >> 4) * 8;
        const int c  = ct * 16 + (l & 15);
        union { __half2 h2[4]; uint4 u; } pk;
#pragma unroll
        for (int j = 0; j < 4; ++j)
            pk.h2[j] = __floats2half2_rn(W2[(kb + 2 * j) * NOUT + c],
                                         W2[(kb + 2 * j + 1) * NOUT + c]);
        *(uint4*)&w2frag[((size_t)bb * 64 + l) * 8] = pk.u;
    } else {
        int i = (b - 20) * 64 + l;
        if (i < NB) gcur[i] = i * CAP;
    }
}

// ---------------------------------------------------------------
// fused (512 threads): blocks [0,NCH) = lean coarse scatter;
// blocks [NCH,..) = MFMA gemm1 writing support in FP8 e4m3
// (64B rows = one cache line; encode/decode use the same HW cvt).
// record: x = src(17b) | dstLocal(8b)<<17 ; y = val f32 bits
// ---------------------------------------------------------------
__global__ __launch_bounds__(512) void g1cs_kernel(const float* __restrict__ x,
                                                   const __half* __restrict__ wfrag,
                                                   unsigned char* __restrict__ support8,
                                                   const float* __restrict__ vals,
                                                   const int* __restrict__ src,
                                                   const int* __restrict__ dst,
                                                   int* __restrict__ gcur,
                                                   uint2* __restrict__ recsC) {
    __shared__ int cnt[NB];
    __shared__ int pos[NB];
    const int tid = threadIdx.x;

    if (blockIdx.x < NCH) {
        const int cbase0 = blockIdx.x * CCH;
        for (int i = tid; i < NB; i += 512) cnt[i] = 0;
        int dstv[CCH / 512];
        __syncthreads();
#pragma unroll
        for (int k = 0; k < CCH / 512; ++k) {
            int e = cbase0 + k * 512 + tid;
            int d = (e < N_EDGES) ? dst[e] : -1;
            dstv[k] = d;
            if (d >= 0) atomicAdd(&cnt[d >> 8], 1);
        }
        __syncthreads();
        for (int b = tid; b < NB; b += 512) {
            int c = cnt[b];
            pos[b] = c ? atomicAdd(&gcur[b], c) : 0;
        }
        __syncthreads();
#pragma unroll
        for (int k = 0; k < CCH / 512; ++k) {
            int e = cbase0 + k * 512 + tid;
            int d = dstv[k];
            if (d >= 0) {
                int b = d >> 8;
                int slot = atomicAdd(&pos[b], 1);
                if (slot < (b + 1) * CAP)
                    recsC[slot] = make_uint2((unsigned)src[e] |
                                             ((unsigned)(d & (NPB - 1)) << 17),
                                             __float_as_uint(vals[e]));
            }
        }
    } else {
        // ------- MFMA gemm1: support = x @ W1 (8 tiles per block) -------
        const int lane = tid & 63;
        const int tile = (blockIdx.x - NCH) * 8 + (tid >> 6);
        const int n0 = tile * 16;
        if (n0 >= N_NODES) return;

        half8 a[4][4];
#pragma unroll
        for (int ks = 0; ks < 4; ++ks)
#pragma unroll
            for (int ct = 0; ct < 4; ++ct)
                a[ks][ct] = *(const half8*)&wfrag[((size_t)(ks * 4 + ct) * 64 + lane) * 8];

        floatx4 acc[4];
#pragma unroll
        for (int ct = 0; ct < 4; ++ct) acc[ct] = (floatx4){0.f, 0.f, 0.f, 0.f};

        const int node = n0 + (lane & 15);
        const float* xrow = x + (size_t)node * NFEAT + (lane >> 4) * 8;

#pragma unroll
        for (int ks = 0; ks < 4; ++ks) {
            float4 f0 = *(const float4*)(xrow + ks * 32);
            float4 f1 = *(const float4*)(xrow + ks * 32 + 4);
            union { __half2 h2[4]; half8 v; } bv;
            bv.h2[0] = __floats2half2_rn(f0.x, f0.y);
            bv.h2[1] = __floats2half2_rn(f0.z, f0.w);
            bv.h2[2] = __floats2half2_rn(f1.x, f1.y);
            bv.h2[3] = __floats2half2_rn(f1.z, f1.w);
#pragma unroll
            for (int ct = 0; ct < 4; ++ct)
                acc[ct] = __builtin_amdgcn_mfma_f32_16x16x32_f16(a[ks][ct], bv.v, acc[ct], 0, 0, 0);
        }

        unsigned char* srow = support8 + (size_t)node * 64 + (lane >> 4) * 4;
#pragma unroll
        for (int ct = 0; ct < 4; ++ct) {
            int p = __builtin_amdgcn_cvt_pk_fp8_f32(acc[ct][0], acc[ct][1], 0, false);
            p = __builtin_amdgcn_cvt_pk_fp8_f32(acc[ct][2], acc[ct][3], p, true);
            *(unsigned*)(srow + ct * 16) = (unsigned)p;
        }
    }
}

// ---------------------------------------------------------------
// fine sort (512 threads): counting-sort each bucket window into
// exact node order; PACK record to 4B: src(17) | fp16val sans sign(15).
// (adj_vals >= 0 so the fp16 sign bit is always 0 -> exact.)
// ---------------------------------------------------------------
__global__ __launch_bounds__(512) void fine_sort_kernel(const int* __restrict__ gcur,
                                                        const uint2* __restrict__ recsC,
                                                        unsigned* __restrict__ recs2,
                                                        int* __restrict__ offs,
                                                        int* __restrict__ ends) {
    __shared__ int cnt[NPB];
    __shared__ int cur[NPB];
    __shared__ int w8[8];
    const int tid = threadIdx.x;
    const int b = blockIdx.x;
    const int s = b * CAP;
    const int e = min(gcur[b], s + CAP);
    if (tid < NPB) cnt[tid] = 0;
    __syncthreads();
    for (int i = s + tid; i < e; i += 512)
        atomicAdd(&cnt[(recsC[i].x >> 17) & (NPB - 1)], 1);
    __syncthreads();
    int v = (tid < NPB) ? cnt[tid] : 0;
    int excl = block_excl_scan_512(v, tid, w8);
    if (tid < NPB) {
        cur[tid] = excl;
        const int node = b * NPB + tid;
        if (node < N_NODES) {
            offs[node] = s + excl;
            ends[node] = s + excl + v;
        }
    }
    __syncthreads();
    for (int i = s + tid; i < e; i += 512) {
        uint2 r = recsC[i];
        int dl = (r.x >> 17) & (NPB - 1);
        unsigned hb = (unsigned)__half_as_ushort(__float2half(__uint_as_float(r.y))) & 0x7FFFu;
        int p = atomicAdd(&cur[dl], 1);
        recs2[s + p] = (r.x & 0x1FFFFu) | (hb << 17);
    }
}

// ---------------------------------------------------------------
// SpMM1: h[d,:64] (fp16) = relu( sum val*support[src,:] + b1 )
// support is FP8 e4m3: 64B row = ONE cache line. wave per node;
// 8 lanes/edge x 8B; cvt_pk_f32_fp8 unpack; f32 accumulate;
// LDS transpose-reduce epilogue.
// ---------------------------------------------------------------
__global__ __launch_bounds__(256) void spmm1_kernel(const int* __restrict__ offs,
                                                    const int* __restrict__ ends,
                                                    const unsigned* __restrict__ recs,
                                                    const unsigned char* __restrict__ support8,
                                                    const float* __restrict__ b1,
                                                    __half* __restrict__ h) {
    __shared__ float red[4][8][65];
    const int tid = threadIdx.x;
    const int lane = tid & 63;
    const int wid = tid >> 6;
    const int d = blockIdx.x * 4 + wid;
    if (d >= N_NODES) return;
    const int g = lane >> 3, q = lane & 7;
    float acc[8];
#pragma unroll
    for (int j = 0; j < 8; ++j) acc[j] = 0.f;

    const int start = offs[d], end = ends[d];
    for (int e = start + g; e < end; e += 8) {
        unsigned r = recs[e];
        float v = __half2float(__ushort_as_half((unsigned short)(r >> 17)));
        uint2 u = *(const uint2*)(support8 + ((size_t)(r & 0x1FFFFu) << 6) + (q << 3));
        floatx2 f0 = __builtin_amdgcn_cvt_pk_f32_fp8((int)u.x, false);
        floatx2 f1 = __builtin_amdgcn_cvt_pk_f32_fp8((int)u.x, true);
        floatx2 f2 = __builtin_amdgcn_cvt_pk_f32_fp8((int)u.y, false);
        floatx2 f3 = __builtin_amdgcn_cvt_pk_f32_fp8((int)u.y, true);
        acc[0] += v * f0[0]; acc[1] += v * f0[1];
        acc[2] += v * f1[0]; acc[3] += v * f1[1];
        acc[4] += v * f2[0]; acc[5] += v * f2[1];
        acc[6] += v * f3[0]; acc[7] += v * f3[1];
    }
#pragma unroll
    for (int j = 0; j < 8; ++j) red[wid][g][q * 8 + j] = acc[j];
    __builtin_amdgcn_wave_barrier();
    float s = 0.f;
#pragma unroll
    for (int gg = 0; gg < 8; ++gg) s += red[wid][gg][lane];
    float hv = fmaxf(s + b1[lane], 0.f);
    h[(size_t)d * NHID + lane] = __float2half(hv);
}

// ---------------------------------------------------------------
// GEMM2 (MFMA): s2[N,32] (fp16) = h[N,64] (fp16) @ W2[64,32]
// ---------------------------------------------------------------
__global__ __launch_bounds__(256) void gemm2_kernel(const __half* __restrict__ h,
                                                    const __half* __restrict__ w2frag,
                                                    __half* __restrict__ s2) {
    const int lane = threadIdx.x & 63;
    const int tile = blockIdx.x * 4 + (threadIdx.x >> 6);
    const int n0 = tile * 16;
    if (n0 >= N_NODES) return;

    half8 a[2][2];
#pragma unroll
    for (int ks = 0; ks < 2; ++ks)
#pragma unroll
        for (int ct = 0; ct < 2; ++ct)
            a[ks][ct] = *(const half8*)&w2frag[((size_t)(ks * 2 + ct) * 64 + lane) * 8];

    floatx4 acc[2];
#pragma unroll
    for (int ct = 0; ct < 2; ++ct) acc[ct] = (floatx4){0.f, 0.f, 0.f, 0.f};

    const int node = n0 + (lane & 15);
    const __half* hrow = h + (size_t)node * NHID + (lane >> 4) * 8;

#pragma unroll
    for (int ks = 0; ks < 2; ++ks) {
        half8 bv = *(const half8*)(hrow + ks * 32);
#pragma unroll
        for (int ct = 0; ct < 2; ++ct)
            acc[ct] = __builtin_amdgcn_mfma_f32_16x16x32_f16(a[ks][ct], bv, acc[ct], 0, 0, 0);
    }

    __half* srow = s2 + (size_t)node * NOUT + (lane >> 4) * 4;
#pragma unroll
    for (int ct = 0; ct < 2; ++ct) {
        union { __half2 h2[2]; uint2 u; } pk;
        pk.h2[0] = __floats2half2_rn(acc[ct][0], acc[ct][1]);
        pk.h2[1] = __floats2half2_rn(acc[ct][2], acc[ct][3]);
        *(uint2*)&srow[ct * 16] = pk.u;
    }
}

// ---------------------------------------------------------------
// SpMM2: out[d,:32] (fp32) = sum val*s2[src,:] + b2
// wave per node; 4 lanes/edge x 16B; packed 4B records; __hfma2.
// ---------------------------------------------------------------
__global__ __launch_bounds__(256) void spmm2_kernel(const int* __restrict__ offs,
                                                    const int* __restrict__ ends,
                                                    const unsigned* __restrict__ recs,
                                                    const __half* __restrict__ dense,
                                                    const float* __restrict__ b2,
                                                    float* __restrict__ out) {
    __shared__ float red[4][16][33];
    const int tid = threadIdx.x;
    const int lane = tid & 63;
    const int wid = tid >> 6;
    const int d = blockIdx.x * 4 + wid;
    if (d >= N_NODES) return;
    const int g = lane >> 2, q4 = lane & 3;
    __half2 hacc[4];
#pragma unroll
    for (int j = 0; j < 4; ++j) hacc[j] = __half2half2(__float2half(0.f));

    const int start = offs[d], end = ends[d];
    const char* dbase = (const char*)dense + (q4 << 4);
    for (int e = start + g; e < end; e += 16) {
        unsigned r = recs[e];
        __half2 hv2 = __half2half2(__ushort_as_half((unsigned short)(r >> 17)));
        union { uint4 u; __half2 h2[4]; } rw;
        rw.u = *(const uint4*)(dbase + ((size_t)(r & 0x1FFFFu) << 6));
#pragma unroll
        for (int j = 0; j < 4; ++j)
            hacc[j] = __hfma2(rw.h2[j], hv2, hacc[j]);
    }
#pragma unroll
    for (int j = 0; j < 4; ++j) {
        float2 f = __half22float2(hacc[j]);
        red[wid][g][q4 * 8 + 2 * j]     = f.x;
        red[wid][g][q4 * 8 + 2 * j + 1] = f.y;
    }
    __builtin_amdgcn_wave_barrier();
    const int c = lane & 31, chunk = lane >> 5;
    float s = 0.f;
#pragma unroll
    for (int t = 0; t < 8; ++t) s += red[wid][chunk * 8 + t][c];
    s += __shfl_xor(s, 32, 64);
    if (chunk == 0) out[(size_t)d * NOUT + c] = s + b2[c];
}

extern "C" void kernel_launch(void* const* d_in, const int* in_sizes, int n_in,
                              void* d_out, int out_size, void* d_ws, size_t ws_size,
                              hipStream_t stream) {
    const float* x        = (const float*)d_in[0];
    const float* adj_vals = (const float*)d_in[1];
    const float* W1       = (const float*)d_in[2];
    const float* b1       = (const float*)d_in[3];
    const float* W2       = (const float*)d_in[4];
    const float* b2       = (const float*)d_in[5];
    const int*   esrc     = (const int*)d_in[6];
    const int*   edst     = (const int*)d_in[7];
    float*       out      = (float*)d_out;

    // ws layout (~48 MB, all regions rewritten every call):
    //   support8[N*64 fp8 = 6.4MB] (s2 fp16 N*32 = 6.4MB aliases; support dead
    //   after spmm1; region reserved 12.8MB) | h[12.8MB]
    //   recsC[NB*CAP*8 = 14.41MB] | recs2[NB*CAP*4 = 7.2MB]
    //   offs | ends | gcur | wfrag | w2frag
    char* W = (char*)d_ws;
    unsigned char* support8 = (unsigned char*)W;
    __half*   h       = (__half*)(W + 12800000);
    uint2*    recsC   = (uint2*)(W + 25600000);
    unsigned* recs2   = (unsigned*)(W + 25600000 + (size_t)NB * CAP * 8);
    int*      IW      = (int*)(W + 25600000 + (size_t)NB * CAP * 12);
    int*      offs    = IW;                      // N
    int*      ends    = IW + 100032;             // N
    int*      gcur    = IW + 200064;             // NB
    __half*   wfrag   = (__half*)(IW + 200064 + 512);   // 8192 halves
    __half*   w2frag  = wfrag + 8192;                   // 2048 halves
    __half*   s2      = (__half*)W;              // aliases support8 region

    // 1. prep: W1/W2 fragment swizzle + gcur init
    prep_kernel<<<20 + (NB + 63) / 64, 64, 0, stream>>>(W1, W2, wfrag, w2frag, gcur);

    // 2. fused: lean coarse scatter | MFMA gemm1 (fp8 support out)
    g1cs_kernel<<<NCH + G1B, 512, 0, stream>>>(x, wfrag, support8,
                                               adj_vals, esrc, edst, gcur, recsC);

    // 3. fine sort -> packed recs2, offs/ends
    fine_sort_kernel<<<NB, 512, 0, stream>>>(gcur, recsC, recs2, offs, ends);

    // 4. h = relu(A @ support + b1)  (fp8 gather, one line per edge)
    spmm1_kernel<<<(N_NODES + 3) / 4, 256, 0, stream>>>(offs, ends, recs2,
                                                        support8, b1, h);

    // 5. s2 = h @ W2  (MFMA, into support region)
    gemm2_kernel<<<(N_NODES / 16 + 3) / 4, 256, 0, stream>>>(h, w2frag, s2);

    // 6. out = A @ s2 + b2
    spmm2_kernel<<<(N_NODES + 3) / 4, 256, 0, stream>>>(offs, ends, recs2,
                                                        s2, b2, out);
}